// Round 4
// baseline (519.856 us; speedup 1.0000x reference)
//
#include <hip/hip_runtime.h>

#define SQ 2048
#define BB 2
#define EE 1024
#define HH 16
#define DD 64
#define MM (SQ*BB)          // 4096 composite rows (s*B + b)
#define LOG2E 1.44269504f

typedef _Float16 f16;
typedef _Float16 half8 __attribute__((ext_vector_type(8)));
typedef _Float16 half4 __attribute__((ext_vector_type(4)));
typedef float f32x4 __attribute__((ext_vector_type(4)));

static __device__ __forceinline__ f32x4 mfma16(half8 a, half8 b, f32x4 c) {
    return __builtin_amdgcn_mfma_f32_16x16x32_f16(a, b, c, 0, 0, 0);
}

// async global->LDS, 16B per lane (GEMM staging only)
static __device__ __forceinline__ void gload16(const f16* g, f16* l) {
    __builtin_amdgcn_global_load_lds(
        (const __attribute__((address_space(1))) unsigned int*)g,
        (__attribute__((address_space(3))) unsigned int*)l, 16, 0, 0);
}

// ---------------- fused elementwise converts ----------------
__global__ void k_elem(const float* __restrict__ q_w, const float* __restrict__ k_w,
                       const float* __restrict__ v_w, const float* __restrict__ query,
                       const float* __restrict__ key, const float* __restrict__ value,
                       const float* __restrict__ owm, const float* __restrict__ owl,
                       const float* __restrict__ eps,
                       f16* qw16, f16* kw16, f16* vw16,
                       f16* xq16, f16* xk16, f16* xv16, f16* ow16)
{
    int y = blockIdx.y;
    size_t i = ((size_t)blockIdx.x * 256 + threadIdx.x) * 4;
    if (y < 3) {
        if (i >= (size_t)EE*EE) return;
        const float* s = (y==0) ? q_w : (y==1) ? k_w : v_w;
        f16* d = (y==0) ? qw16 : (y==1) ? kw16 : vw16;
        float4 v = *(const float4*)&s[i];
        half4 o = {(f16)v.x, (f16)v.y, (f16)v.z, (f16)v.w};
        *(half4*)&d[i] = o;
    } else if (y < 6) {
        const float* s = (y==3) ? query : (y==4) ? key : value;
        f16* d = (y==3) ? xq16 : (y==4) ? xk16 : xv16;
        float4 v = *(const float4*)&s[i];
        half4 o = {(f16)v.x, (f16)v.y, (f16)v.z, (f16)v.w};
        *(half4*)&d[i] = o;
    } else {
        if (i >= (size_t)EE*EE) return;
        float4 m = *(const float4*)&owm[i];
        float4 l = *(const float4*)&owl[i];
        float4 e = *(const float4*)&eps[i];
        half4 o = {(f16)(m.x + e.x * __expf(l.x)), (f16)(m.y + e.y * __expf(l.y)),
                   (f16)(m.z + e.z * __expf(l.z)), (f16)(m.w + e.w * __expf(l.w))};
        *(half4*)&ow16[i] = o;
    }
}

// ---------------- GEMM body: C[M,N] = (A[M,K] @ W[N,K]^T + bias) * scale ----------------
// m97-style 128x128 tile, BK=32, 4 waves each 64x64 (4x4 MFMA tiles).
// global_load_lds staging, XOR-of-(row&3) chunk swizzle (conflict-free b128 frag reads).
__device__ __forceinline__ void gemm_body(
    const f16* __restrict__ A, const f16* __restrict__ W,
    const float* __restrict__ bias, float scale, void* __restrict__ out, int mode)
{
    __shared__ f16 As[128*32];
    __shared__ f16 Bs[128*32];
    int t = threadIdx.x, lane = t & 63, w = t >> 6;
    int quad = lane >> 4, m16 = lane & 15;
    int wm = w >> 1, wn = w & 1;
    int gm0 = blockIdx.x * 128, gn0 = blockIdx.y * 128;
    f32x4 acc[4][4] = {};
    for (int kt = 0; kt < EE; kt += 32) {
        #pragma unroll
        for (int i = 0; i < 2; ++i) {
            int c = t + i * 256;
            int row = c >> 2, pch = c & 3;
            int lch = pch ^ (row & 3);
            gload16(&A[(size_t)(gm0+row)*EE + kt + lch*8], &As[row*32 + pch*8]);
            gload16(&W[(size_t)(gn0+row)*EE + kt + lch*8], &Bs[row*32 + pch*8]);
        }
        __syncthreads();
        int cs = (quad ^ (m16 & 3)) * 8;
        half8 af[4], bf[4];
        #pragma unroll
        for (int i = 0; i < 4; ++i) af[i] = *(half8*)&As[(wm*64 + i*16 + m16)*32 + cs];
        #pragma unroll
        for (int j = 0; j < 4; ++j) bf[j] = *(half8*)&Bs[(wn*64 + j*16 + m16)*32 + cs];
        #pragma unroll
        for (int i = 0; i < 4; ++i)
            #pragma unroll
            for (int j = 0; j < 4; ++j)
                acc[i][j] = mfma16(af[i], bf[j], acc[i][j]);
        __syncthreads();
    }
    // C/D layout: col = lane&15, row = quad*4 + reg
    #pragma unroll
    for (int j = 0; j < 4; ++j) {
        int col = gn0 + wn*64 + j*16 + m16;
        float bb = bias ? bias[col] : 0.0f;
        #pragma unroll
        for (int i = 0; i < 4; ++i) {
            int r0 = gm0 + wm*64 + i*16 + quad*4;
            #pragma unroll
            for (int r = 0; r < 4; ++r) {
                float v = (acc[i][j][r] + bb) * scale;
                int m = r0 + r;
                if (mode == 2)      ((float*)out)[(size_t)m*EE + col] = v;
                else if (mode == 1) ((f16*)out)[((size_t)(m & 1)*EE + col)*SQ + (m >> 1)] = (f16)v;
                else                ((f16*)out)[(size_t)m*EE + col] = (f16)v;
            }
        }
    }
}

__global__ __launch_bounds__(256, 3) void k_gemm_qkv(
    const f16* xq, const f16* qw, const float* qb,
    const f16* xk, const f16* kw, const float* kb,
    const f16* xv, const f16* vw, const float* vb,
    f16* Q16, f16* K16, f16* Vt16)
{
    int z = blockIdx.z;
    const f16* A = (z==0) ? xq : (z==1) ? xk : xv;
    const f16* W = (z==0) ? qw : (z==1) ? kw : vw;
    const float* bi = (z==0) ? qb : (z==1) ? kb : vb;
    float sc = (z==0) ? 0.125f * LOG2E : 1.0f;   // fold log2e into Q
    void* o = (z==0) ? (void*)Q16 : (z==1) ? (void*)K16 : (void*)Vt16;
    gemm_body(A, W, bi, sc, o, (z==2) ? 1 : 0);
}

__global__ __launch_bounds__(256, 3) void k_gemm_o(const f16* A, const f16* W, float* out)
{
    gemm_body(A, W, nullptr, 1.0f, out, 2);
}

// ---------------- phase 1: lse2[b,h,q] = log2(sum_k 2^s2) ----------------
__global__ __launch_bounds__(256, 4) void k_lse(
    const f16* __restrict__ Q16, const f16* __restrict__ K16, float* __restrict__ lse2)
{
    __shared__ float red[4][64];
    const int t = threadIdx.x, lane = t & 63, w = t >> 6;
    const int quad = lane >> 4, m16 = lane & 15;
    const int q0 = blockIdx.x * 64, h = blockIdx.y, b = blockIdx.z;

    half8 bq[4][2];
    #pragma unroll
    for (int nt = 0; nt < 4; ++nt)
        #pragma unroll
        for (int dk = 0; dk < 2; ++dk)
            bq[nt][dk] = *(const half8*)&Q16[(size_t)((q0 + nt*16 + m16)*BB + b)*EE + h*DD + dk*32 + quad*8];

    float lsum[4] = {};
    for (int kt = 0; kt < 16; ++kt) {
        half8 ak[2][2];
        #pragma unroll
        for (int mt = 0; mt < 2; ++mt)
            #pragma unroll
            for (int dk = 0; dk < 2; ++dk)
                ak[mt][dk] = *(const half8*)&K16[(size_t)((kt*128 + w*32 + mt*16 + m16)*BB + b)*EE + h*DD + dk*32 + quad*8];
        #pragma unroll
        for (int mt = 0; mt < 2; ++mt)
            #pragma unroll
            for (int nt = 0; nt < 4; ++nt) {
                f32x4 s = {};
                s = mfma16(ak[mt][0], bq[nt][0], s);   // S^T: rows k, cols q
                s = mfma16(ak[mt][1], bq[nt][1], s);
                lsum[nt] += __builtin_amdgcn_exp2f(s[0]) + __builtin_amdgcn_exp2f(s[1])
                          + __builtin_amdgcn_exp2f(s[2]) + __builtin_amdgcn_exp2f(s[3]);
            }
    }
    #pragma unroll
    for (int nt = 0; nt < 4; ++nt) {
        float v = lsum[nt];
        v += __shfl_xor(v, 16, 64);
        v += __shfl_xor(v, 32, 64);
        lsum[nt] = v;
    }
    if (quad == 0)
        #pragma unroll
        for (int nt = 0; nt < 4; ++nt) red[w][nt*16 + m16] = lsum[nt];
    __syncthreads();
    if (t < 64) {
        float v = red[0][t] + red[1][t] + red[2][t] + red[3][t];
        lse2[((size_t)b*HH + h)*SQ + q0 + t] = __log2f(v);
    }
}

// ---------------- avg_attn: register-only streamer, ZERO barriers ----------------
// grid (SQ/64, SQ/256, B) = (32,8,2) = 512 wgs. wg owns avg[b, q0..+63, k0..+255];
// wave w owns k-strip 64. Loops h, accumulating p in lane-exclusive regs.
__global__ __launch_bounds__(256, 2) void k_avg(
    const f16* __restrict__ Q16, const f16* __restrict__ K16,
    const float* __restrict__ lse2, float* __restrict__ avg_out)
{
    const int t = threadIdx.x, lane = t & 63, w = t >> 6;
    const int quad = lane >> 4, m16 = lane & 15;
    const int q0 = blockIdx.x * 64, k0 = blockIdx.y * 256, b = blockIdx.z;
    const int kw = k0 + w * 64;

    float avg_r[4][4][4] = {};   // [mt(k16)][nt(q16)][r]
    for (int h = 0; h < HH; ++h) {
        float c[4];
        #pragma unroll
        for (int nt = 0; nt < 4; ++nt)
            c[nt] = lse2[((size_t)b*HH + h)*SQ + q0 + nt*16 + m16];
        half8 bq[4][2], ak[4][2];
        #pragma unroll
        for (int nt = 0; nt < 4; ++nt)
            #pragma unroll
            for (int dk = 0; dk < 2; ++dk)
                bq[nt][dk] = *(const half8*)&Q16[(size_t)((q0 + nt*16 + m16)*BB + b)*EE + h*DD + dk*32 + quad*8];
        #pragma unroll
        for (int mt = 0; mt < 4; ++mt)
            #pragma unroll
            for (int dk = 0; dk < 2; ++dk)
                ak[mt][dk] = *(const half8*)&K16[(size_t)((kw + mt*16 + m16)*BB + b)*EE + h*DD + dk*32 + quad*8];
        #pragma unroll
        for (int mt = 0; mt < 4; ++mt)
            #pragma unroll
            for (int nt = 0; nt < 4; ++nt) {
                f32x4 s = {};
                s = mfma16(ak[mt][0], bq[nt][0], s);
                s = mfma16(ak[mt][1], bq[nt][1], s);
                #pragma unroll
                for (int r = 0; r < 4; ++r)
                    avg_r[mt][nt][r] += __builtin_amdgcn_exp2f(s[r] - c[nt]);
            }
    }
    #pragma unroll
    for (int mt = 0; mt < 4; ++mt)
        #pragma unroll
        for (int nt = 0; nt < 4; ++nt) {
            int q = q0 + nt*16 + m16;
            int k = kw + mt*16 + quad*4;
            float4 v = { avg_r[mt][nt][0]*(1.0f/HH), avg_r[mt][nt][1]*(1.0f/HH),
                         avg_r[mt][nt][2]*(1.0f/HH), avg_r[mt][nt][3]*(1.0f/HH) };
            *(float4*)&avg_out[((size_t)b*SQ + q)*SQ + k] = v;
        }
}

// ---------------- ctx: flash-style, ZERO barriers, private LDS bounce ----------------
// grid (SQ/64, HH, B) = (32,16,2) = 1024 wgs. Wave w owns q-strip (q0 + w*16).
// S^T C/D lanes hold q=lane&15 == PV A-operand row -> per-wave private ps bounce
// (same-wave LDS RAW, ordered by lgkmcnt only; no __syncthreads in the kernel).
// K/V fragments direct from global; 4 waves of a wg share them through L1.
__global__ __launch_bounds__(256, 2) void k_ctx(
    const f16* __restrict__ Q16, const f16* __restrict__ K16, const f16* __restrict__ Vt16,
    const float* __restrict__ lse2, f16* __restrict__ ctx16)
{
    __shared__ f16 psb[4][16*136];   // per-wave private bounce, stride 136 halves
    const int t = threadIdx.x, lane = t & 63, w = t >> 6;
    const int quad = lane >> 4, m16 = lane & 15;
    const int qw = blockIdx.x * 64 + w * 16;
    const int h = blockIdx.y, b = blockIdx.z;
    f16* ps = psb[w];

    // Q fragments for this wave's 16 q rows: persistent in registers
    half8 bq[2];
    #pragma unroll
    for (int dk = 0; dk < 2; ++dk)
        bq[dk] = *(const half8*)&Q16[(size_t)((qw + m16)*BB + b)*EE + h*DD + dk*32 + quad*8];
    const float c = lse2[((size_t)b*HH + h)*SQ + qw + m16];   // per-lane: q = m16 col

    f32x4 acc[4] = {};   // ctx[16q x 64d], wave-complete (no partials)
    for (int kt = 0; kt < SQ/128; ++kt) {
        // QK^T: S^T[128k x 16q] in 8 tiles; exp2; bounce to ps[q][k]
        #pragma unroll
        for (int mt = 0; mt < 8; ++mt) {
            half8 ak0 = *(const half8*)&K16[(size_t)((kt*128 + mt*16 + m16)*BB + b)*EE + h*DD + quad*8];
            half8 ak1 = *(const half8*)&K16[(size_t)((kt*128 + mt*16 + m16)*BB + b)*EE + h*DD + 32 + quad*8];
            f32x4 s = {};
            s = mfma16(ak0, bq[0], s);
            s = mfma16(ak1, bq[1], s);
            half4 ph;
            #pragma unroll
            for (int r = 0; r < 4; ++r)
                ph[r] = (f16)__builtin_amdgcn_exp2f(s[r] - c);
            // lane holds q=m16 (col), k = mt*16 + quad*4 + r (row)
            *(half4*)&ps[m16*136 + mt*16 + quad*4] = ph;
        }
        // PV: ctx[16q x 64d] += P[16q x 128k] @ V[128k x 64d]
        #pragma unroll
        for (int ks = 0; ks < 4; ++ks) {
            half8 ap = *(half8*)&ps[m16*136 + ks*32 + quad*8];   // A: [q=m16][k]
            #pragma unroll
            for (int dt = 0; dt < 4; ++dt) {
                half8 bv = *(const half8*)&Vt16[((size_t)b*EE + h*DD + dt*16 + m16)*SQ + kt*128 + ks*32 + quad*8];
                acc[dt] = mfma16(ap, bv, acc[dt]);
            }
        }
    }
    // C/D: col = lane&15 = d, row = quad*4 + r = q
    #pragma unroll
    for (int dt = 0; dt < 4; ++dt)
        #pragma unroll
        for (int r = 0; r < 4; ++r) {
            int q = qw + quad*4 + r;
            ctx16[(size_t)(q*BB + b)*EE + h*DD + dt*16 + m16] = (f16)acc[dt][r];
        }
}

// ---------------- launch ----------------
extern "C" void kernel_launch(void* const* d_in, const int* in_sizes, int n_in,
                              void* d_out, int out_size, void* d_ws, size_t ws_size,
                              hipStream_t stream) {
    const float* query    = (const float*)d_in[0];
    const float* key      = (const float*)d_in[1];
    const float* value    = (const float*)d_in[2];
    const float* q_w      = (const float*)d_in[3];
    const float* q_b      = (const float*)d_in[4];
    const float* k_w      = (const float*)d_in[5];
    const float* k_b      = (const float*)d_in[6];
    const float* v_w      = (const float*)d_in[7];
    const float* v_b      = (const float*)d_in[8];
    const float* o_w_mean = (const float*)d_in[9];
    const float* o_w_lgstd= (const float*)d_in[10];
    const float* eps      = (const float*)d_in[11];
    float* out = (float*)d_out;                  // [S,B,E] fp32
    float* avg = out + (size_t)MM * EE;          // [B,S,S] fp32

    const size_t EWN = (size_t)EE*EE;   // 1M
    const size_t XWN = (size_t)MM*EE;   // 4M
    f16* qw16  = (f16*)d_ws;
    f16* kw16  = qw16 + EWN;
    f16* vw16  = kw16 + EWN;
    f16* ow16  = vw16 + EWN;
    f16* Q16   = ow16 + EWN;
    f16* K16   = Q16  + XWN;
    f16* Vt16  = K16  + XWN;
    f16* ctx16 = Vt16 + XWN;
    float* lse2 = (float*)(ctx16 + XWN);             // B*H*S fp32
    f16* xq16  = (f16*)(lse2 + (size_t)BB*HH*SQ);
    f16* xk16  = xq16 + XWN;
    f16* xv16  = xk16 + XWN;

    k_elem<<<dim3(XWN/1024, 7), 256, 0, stream>>>(q_w, k_w, v_w, query, key, value,
        o_w_mean, o_w_lgstd, eps, qw16, kw16, vw16, xq16, xk16, xv16, ow16);

    k_gemm_qkv<<<dim3(MM/128, EE/128, 3), 256, 0, stream>>>(
        xq16, qw16, q_b, xk16, kw16, k_b, xv16, vw16, v_b, Q16, K16, Vt16);

    k_lse<<<dim3(SQ/64, HH, BB), 256, 0, stream>>>(Q16, K16, lse2);
    k_avg<<<dim3(SQ/64, SQ/256, BB), 256, 0, stream>>>(Q16, K16, lse2, avg);
    k_ctx<<<dim3(SQ/64, HH, BB), 256, 0, stream>>>(Q16, K16, Vt16, lse2, ctx16);

    k_gemm_o<<<dim3(MM/128, EE/128), 256, 0, stream>>>(ctx16, ow16, out);
}